// Round 6
// baseline (149.061 us; speedup 1.0000x reference)
//
#include <hip/hip_runtime.h>
#include <cstddef>

// Problem constants
#define BB 4
#define CCH 256     // C
#define C2 128      // C/2
#define NN 4096     // T*H*W
#define PM 384      // 3*C2
#define KVS 32      // split-K slices for K*V^T (128 n each)

typedef __attribute__((ext_vector_type(8))) short short8v;   // 8 bf16
typedef __attribute__((ext_vector_type(4))) short short4v;   // 4 bf16
typedef __attribute__((ext_vector_type(4))) float f32x4;

static __device__ __forceinline__ short f2bf(float f) {
    union { float f; unsigned u; } c; c.f = f;
    unsigned r = (c.u + 0x7FFFu + ((c.u >> 16) & 1u)) >> 16;
    return (short)r;
}

// ---------------- pack W (bf16) + biases + Wo (bf16) ------------------------
__global__ __launch_bounds__(256) void k_pack(
    const float* __restrict__ Wq, const float* __restrict__ bq,
    const float* __restrict__ Wk, const float* __restrict__ bk,
    const float* __restrict__ Wv, const float* __restrict__ bv,
    const float* __restrict__ Wo,
    short* __restrict__ wpackh, float* __restrict__ bpack,
    short* __restrict__ Woh)
{
    const int m = blockIdx.x;     // 0..639
    const int c = threadIdx.x;    // 0..255
    if (m < PM) {
        const float* w; const float* bs; int mm;
        if (m < C2)        { w = Wq; bs = bq; mm = m; }
        else if (m < 2*C2) { w = Wk; bs = bk; mm = m - C2; }
        else               { w = Wv; bs = bv; mm = m - 2*C2; }
        wpackh[m * CCH + c] = f2bf(w[mm * CCH + c]);
        if (c == 0) bpack[m] = bs[mm];
    } else {
        const int o = m - PM;     // 0..255
        if (c < C2) Woh[o * C2 + c] = f2bf(Wo[o * C2 + c]);
    }
}

// ---------------- XpH[b][c][n] = bf16(X + pe) -------------------------------
__global__ __launch_bounds__(256) void k_xph(
    const float* __restrict__ X, const float* __restrict__ pe,
    short* __restrict__ XpH)
{
    const size_t e8 = ((size_t)blockIdx.x * 256 + threadIdx.x) * 8;
    const size_t r  = e8 & (size_t)(CCH * NN - 1);   // index within one batch
    float4 x0 = *(const float4*)&X[e8];
    float4 x1 = *(const float4*)&X[e8 + 4];
    float4 p0 = *(const float4*)&pe[r];
    float4 p1 = *(const float4*)&pe[r + 4];
    short8v o;
    o[0] = f2bf(x0.x + p0.x); o[1] = f2bf(x0.y + p0.y);
    o[2] = f2bf(x0.z + p0.z); o[3] = f2bf(x0.w + p0.w);
    o[4] = f2bf(x1.x + p1.x); o[5] = f2bf(x1.y + p1.y);
    o[6] = f2bf(x1.z + p1.z); o[7] = f2bf(x1.w + p1.w);
    *(short8v*)&XpH[e8] = o;
}

// ---------------- QKV projection (bf16 MFMA), bf16 outputs ------------------
// qkv[m][n] = sum_c W[m][c]*Xp[c][n] + bias[m] + task[m%128][n]
// Outputs: sel0 -> qt[b][n][i] (transposed), sel1 -> kk[b][i][n], sel2 -> vv.
#define LROW 40
#define TSP  136
__global__ __launch_bounds__(256) void k_projm(
    const short* __restrict__ XpH,
    const float* __restrict__ tq, const float* __restrict__ tk,
    const float* __restrict__ tv,
    const short* __restrict__ wpackh, const float* __restrict__ bpack,
    short* __restrict__ qt, short* __restrict__ kk, short* __restrict__ vv)
{
    __shared__ short smem[17408];      // max(As+Bs=10240, Ts=128*136=17408)
    short* As = smem;                  // [128 m][40] bf16 (rows of W)
    short* Bs = smem + 5120;           // [128 n][40] bf16 ([n][k] of Xp)
    const int b  = blockIdx.z;
    const int m0 = blockIdx.y * 128;   // 0,128,256
    const int n0 = blockIdx.x * 128;
    const int tid  = threadIdx.x;
    const int wave = tid >> 6;
    const int lane = tid & 63;
    const int lr = lane & 15, lg = lane >> 4;
    const int wm = wave >> 1, wn = wave & 1;   // 2x2 wave grid, 64x64 each
    const short* __restrict__ Xb = XpH + (size_t)b * CCH * NN;

    const int am  = tid >> 1;         // A stage: m row
    const int akb = tid & 1;          // A stage: 16-short half
    const int cq  = tid >> 5;         // B stage: c-quad
    const int nq  = tid & 31;         // B stage: n-quad

    f32x4 acc[4][4];
#pragma unroll
    for (int i = 0; i < 4; ++i)
#pragma unroll
        for (int j = 0; j < 4; ++j) acc[i][j] = (f32x4){0.f, 0.f, 0.f, 0.f};

    for (int k0 = 0; k0 < CCH; k0 += 32) {
        // stage A: 128m x 32k
        {
            const size_t gsrc = (size_t)(m0 + am) * CCH + k0 + akb * 16;
            *(short8v*)&As[am * LROW + akb * 16]     = *(const short8v*)&wpackh[gsrc];
            *(short8v*)&As[am * LROW + akb * 16 + 8] = *(const short8v*)&wpackh[gsrc + 8];
        }
        // stage B: transpose 32c x 128n of XpH -> [n][k] bf16
        short sreg[4][4];
#pragma unroll
        for (int j = 0; j < 4; ++j) {
            const int c = k0 + cq * 4 + j;
            short4v xv = *(const short4v*)&Xb[(size_t)c * NN + n0 + nq * 4];
            sreg[j][0] = xv.x; sreg[j][1] = xv.y; sreg[j][2] = xv.z; sreg[j][3] = xv.w;
        }
#pragma unroll
        for (int i = 0; i < 4; ++i) {
            short4v v; v.x = sreg[0][i]; v.y = sreg[1][i]; v.z = sreg[2][i]; v.w = sreg[3][i];
            *(short4v*)&Bs[(nq * 4 + i) * LROW + cq * 4] = v;
        }
        __syncthreads();
        short8v a[4], bfr[4];
#pragma unroll
        for (int fm = 0; fm < 4; ++fm)
            a[fm] = *(const short8v*)&As[(wm * 64 + fm * 16 + lr) * LROW + lg * 8];
#pragma unroll
        for (int fn = 0; fn < 4; ++fn)
            bfr[fn] = *(const short8v*)&Bs[(wn * 64 + fn * 16 + lr) * LROW + lg * 8];
#pragma unroll
        for (int fm = 0; fm < 4; ++fm)
#pragma unroll
            for (int fn = 0; fn < 4; ++fn)
                acc[fm][fn] = __builtin_amdgcn_mfma_f32_16x16x32_bf16(
                    a[fm], bfr[fn], acc[fm][fn], 0, 0, 0);
        __syncthreads();
    }

    // epilogue: + bias + task, bf16, re-layout through LDS (Ts aliases As/Bs)
    short* Ts = smem;
    const int sel = m0 >> 7;
    if (sel == 0) {
#pragma unroll
        for (int fm = 0; fm < 4; ++fm)
#pragma unroll
            for (int fn = 0; fn < 4; ++fn) {
                const int n_l  = wn * 64 + fn * 16 + lr;
                const int m_lb = wm * 64 + fm * 16 + lg * 4;
                short4v v;
#pragma unroll
                for (int r = 0; r < 4; ++r) {
                    const int m_l = m_lb + r;
                    v[r] = f2bf(acc[fm][fn][r] + bpack[m_l]
                                + tq[(size_t)m_l * NN + n0 + n_l]);
                }
                *(short4v*)&Ts[n_l * TSP + m_lb] = v;
            }
        __syncthreads();
        const int n_l = tid >> 1, half = tid & 1;
        short* dst = qt + (size_t)b * NN * C2 + (size_t)(n0 + n_l) * C2 + half * 64;
        const short* src = &Ts[n_l * TSP + half * 64];
#pragma unroll
        for (int q2 = 0; q2 < 8; ++q2)
            *(short8v*)&dst[q2 * 8] = *(const short8v*)&src[q2 * 8];
    } else {
        const float* __restrict__ task = (sel == 1) ? tk : tv;
        short* kv = (sel == 1) ? kk : vv;
#pragma unroll
        for (int fm = 0; fm < 4; ++fm)
#pragma unroll
            for (int fn = 0; fn < 4; ++fn) {
                const int n_l = wn * 64 + fn * 16 + lr;
#pragma unroll
                for (int r = 0; r < 4; ++r) {
                    const int m_l = wm * 64 + fm * 16 + lg * 4 + r;
                    Ts[m_l * TSP + n_l] =
                        f2bf(acc[fm][fn][r] + bpack[m0 + m_l]
                             + task[(size_t)m_l * NN + n0 + n_l]);
                }
            }
        __syncthreads();
        const int m_l = tid >> 1, half = tid & 1;
        short* dst = kv + (size_t)b * C2 * NN + (size_t)m_l * NN + n0 + half * 64;
        const short* src = &Ts[m_l * TSP + half * 64];
#pragma unroll
        for (int q2 = 0; q2 < 8; ++q2)
            *(short8v*)&dst[q2 * 8] = *(const short8v*)&src[q2 * 8];
    }
}

// ---------------- Mpart[b][s] = K-slice · V-slice^T  (MFMA, no LDS) ---------
__global__ __launch_bounds__(256) void k_kv(
    const short* __restrict__ kk, const short* __restrict__ vv,
    float* __restrict__ Mpart)
{
    const int b = blockIdx.y, s = blockIdx.x;
    const int tid = threadIdx.x;
    const int wave = tid >> 6, lane = tid & 63;
    const int lr = lane & 15, lg = lane >> 4;
    const int wi = wave >> 1, wj = wave & 1;
    const short* Kb = kk + (size_t)b * C2 * NN;
    const short* Vb = vv + (size_t)b * C2 * NN;
    const int nbase = s * 128;
    f32x4 acc[4][4];
#pragma unroll
    for (int i = 0; i < 4; ++i)
#pragma unroll
        for (int j = 0; j < 4; ++j) acc[i][j] = (f32x4){0.f, 0.f, 0.f, 0.f};

    for (int ks = 0; ks < 4; ++ks) {
        const int nn = nbase + ks * 32 + lg * 8;
        short8v a[4], bv8[4];
#pragma unroll
        for (int fi = 0; fi < 4; ++fi)
            a[fi] = *(const short8v*)&Kb[(size_t)(wi * 64 + fi * 16 + lr) * NN + nn];
#pragma unroll
        for (int fj = 0; fj < 4; ++fj)
            bv8[fj] = *(const short8v*)&Vb[(size_t)(wj * 64 + fj * 16 + lr) * NN + nn];
#pragma unroll
        for (int fi = 0; fi < 4; ++fi)
#pragma unroll
            for (int fj = 0; fj < 4; ++fj)
                acc[fi][fj] = __builtin_amdgcn_mfma_f32_16x16x32_bf16(
                    a[fi], bv8[fj], acc[fi][fj], 0, 0, 0);
    }
    float* Mp = Mpart + ((size_t)b * KVS + s) * C2 * C2;
#pragma unroll
    for (int fi = 0; fi < 4; ++fi)
#pragma unroll
        for (int fj = 0; fj < 4; ++fj) {
            const int j = wj * 64 + fj * 16 + lr;
#pragma unroll
            for (int r = 0; r < 4; ++r) {
                const int i = wi * 64 + fi * 16 + lg * 4 + r;
                Mp[(size_t)i * C2 + j] = acc[fi][fj][r];
            }
        }
}

// ---------------- reduce partials, emit Mt[b][j][i] bf16 --------------------
__global__ __launch_bounds__(256) void k_kvred(
    const float* __restrict__ Mpart, short* __restrict__ Mt)
{
    const int b = blockIdx.y;
    const int i = blockIdx.x * 16 + (threadIdx.x >> 4);   // grid.x=8 -> i 0..127
    const int j0 = (threadIdx.x & 15) * 8;
    const float* p = Mpart + (size_t)b * KVS * C2 * C2 + (size_t)i * C2 + j0;
    float a8[8];
#pragma unroll
    for (int e = 0; e < 8; ++e) a8[e] = 0.f;
    for (int s = 0; s < KVS; ++s) {
        float4 v0 = *(const float4*)&p[(size_t)s * C2 * C2];
        float4 v1 = *(const float4*)&p[(size_t)s * C2 * C2 + 4];
        a8[0] += v0.x; a8[1] += v0.y; a8[2] += v0.z; a8[3] += v0.w;
        a8[4] += v1.x; a8[5] += v1.y; a8[6] += v1.z; a8[7] += v1.w;
    }
    short* mt = Mt + (size_t)b * C2 * C2;
#pragma unroll
    for (int e = 0; e < 8; ++e)
        mt[(size_t)(j0 + e) * C2 + i] = f2bf(a8[e]);
}

// ---------------- fused: P = Q·M rows {n==g mod 32}, then out = Wo·P + X ----
// Block (g, jh, b): phase1 computes P[c][j'] = out3[c*32+g][jh*64+j'] via MFMA
// into LDS; phase2 computes out[o][g*128+jh*64+j'] = sum_c Wo[o][c]*P[c][j']+X.
#define PSP 136
__global__ __launch_bounds__(256) void k_qmfinal(
    const short* __restrict__ qt, const short* __restrict__ Mt,
    const short* __restrict__ Woh,
    const float* __restrict__ X, float* __restrict__ out)
{
    __shared__ short Ps[64 * PSP];    // [j'][c] bf16, c contiguous
    const int g  = blockIdx.x;        // 0..31
    const int jh = blockIdx.y;        // 0..1
    const int b  = blockIdx.z;
    const int tid = threadIdx.x;
    const int wave = tid >> 6, lane = tid & 63;
    const int lr = lane & 15, lg = lane >> 4;
    const short* Qb = qt + (size_t)b * NN * C2;
    const short* Mb = Mt + (size_t)b * C2 * C2;

    // ---- phase 1: P[c][j'] = sum_i qt[c*32+g][i] * Mt[j][i]
    {
        const int wc = wave >> 1, wj = wave & 1;   // c-half x j-quarter
        f32x4 acc1[4][2];
#pragma unroll
        for (int i = 0; i < 4; ++i)
#pragma unroll
            for (int j = 0; j < 2; ++j) acc1[i][j] = (f32x4){0.f, 0.f, 0.f, 0.f};
        for (int ks = 0; ks < 4; ++ks) {
            const int kb = ks * 32 + lg * 8;
            short8v a1[4], b1[2];
#pragma unroll
            for (int fc = 0; fc < 4; ++fc) {
                const int c = wc * 64 + fc * 16 + lr;
                a1[fc] = *(const short8v*)&Qb[(size_t)(c * 32 + g) * C2 + kb];
            }
#pragma unroll
            for (int fj = 0; fj < 2; ++fj) {
                const int j = jh * 64 + wj * 32 + fj * 16 + lr;
                b1[fj] = *(const short8v*)&Mb[(size_t)j * C2 + kb];
            }
#pragma unroll
            for (int fc = 0; fc < 4; ++fc)
#pragma unroll
                for (int fj = 0; fj < 2; ++fj)
                    acc1[fc][fj] = __builtin_amdgcn_mfma_f32_16x16x32_bf16(
                        a1[fc], b1[fj], acc1[fc][fj], 0, 0, 0);
        }
        // D: row=c (lg*4+r), col=j' (lr). Store Ps[j'][c] (short4v along c).
#pragma unroll
        for (int fc = 0; fc < 4; ++fc)
#pragma unroll
            for (int fj = 0; fj < 2; ++fj) {
                const int jp = wj * 32 + fj * 16 + lr;
                const int c0 = wc * 64 + fc * 16 + lg * 4;
                short4v v;
#pragma unroll
                for (int r = 0; r < 4; ++r) v[r] = f2bf(acc1[fc][fj][r]);
                *(short4v*)&Ps[jp * PSP + c0] = v;
            }
    }
    __syncthreads();

    // ---- phase 2: out[o][p] = sum_c Wo[o][c] * P[c][j'] + X, o = wave*64+...
    {
        f32x4 acc2[4][4];
#pragma unroll
        for (int i = 0; i < 4; ++i)
#pragma unroll
            for (int j = 0; j < 4; ++j) acc2[i][j] = (f32x4){0.f, 0.f, 0.f, 0.f};
        for (int ks = 0; ks < 4; ++ks) {
            const int kb = ks * 32 + lg * 8;
            short8v a2[4], b2[4];
#pragma unroll
            for (int fo = 0; fo < 4; ++fo) {
                const int o = wave * 64 + fo * 16 + lr;
                a2[fo] = *(const short8v*)&Woh[(size_t)o * C2 + kb];
            }
#pragma unroll
            for (int fj = 0; fj < 4; ++fj)
                b2[fj] = *(const short8v*)&Ps[(fj * 16 + lr) * PSP + kb];
#pragma unroll
            for (int fo = 0; fo < 4; ++fo)
#pragma unroll
                for (int fj = 0; fj < 4; ++fj)
                    acc2[fo][fj] = __builtin_amdgcn_mfma_f32_16x16x32_bf16(
                        a2[fo], b2[fj], acc2[fo][fj], 0, 0, 0);
        }
        const float* Xb = X + (size_t)b * CCH * NN;
        float* Ob = out + (size_t)b * CCH * NN;
#pragma unroll
        for (int fo = 0; fo < 4; ++fo)
#pragma unroll
            for (int fj = 0; fj < 4; ++fj) {
                const int p = g * 128 + jh * 64 + fj * 16 + lr;
                const int ob = wave * 64 + fo * 16 + lg * 4;
#pragma unroll
                for (int r = 0; r < 4; ++r) {
                    const size_t ad = (size_t)(ob + r) * NN + p;
                    Ob[ad] = acc2[fo][fj][r] + Xb[ad];
                }
            }
    }
}

extern "C" void kernel_launch(void* const* d_in, const int* in_sizes, int n_in,
                              void* d_out, int out_size, void* d_ws, size_t ws_size,
                              hipStream_t stream) {
    const float* X  = (const float*)d_in[0];
    const float* pe = (const float*)d_in[1];
    const float* tq = (const float*)d_in[2];
    const float* tk = (const float*)d_in[3];
    const float* tv = (const float*)d_in[4];
    const float* Wq = (const float*)d_in[5];
    const float* bq = (const float*)d_in[6];
    const float* Wk = (const float*)d_in[7];
    const float* bk = (const float*)d_in[8];
    const float* Wv = (const float*)d_in[9];
    const float* bv = (const float*)d_in[10];
    const float* Wo = (const float*)d_in[11];
    float* out = (float*)d_out;

    // Workspace (floats), total ~21.4 MB. Mpart ALIASES XpH (XpH dead after
    // k_projm; k_kv writes Mpart strictly after — stream order).
    float* ws     = (float*)d_ws;
    float* bpack  = ws;                                  // 512
    short* wpackh = (short*)(ws + 512);                  // 98304 sh
    short* Woh    = (short*)(ws + 512 + 49152);          // 32768 sh
    short* qt     = (short*)(ws + 512 + 49152 + 16384);
    short* kk     = qt + (size_t)BB * NN * C2;
    short* vv     = kk + (size_t)BB * NN * C2;
    short* Mt     = vv + (size_t)BB * NN * C2;           // 65536 sh
    short* XpH    = Mt + (size_t)BB * C2 * C2;           // 4194304 sh
    float* Mpart  = (float*)XpH;                         // 2097152 f (alias)

    k_pack<<<dim3(PM + CCH), dim3(256), 0, stream>>>(
        Wq, bq, Wk, bk, Wv, bv, Wo, wpackh, bpack, Woh);
    k_xph<<<dim3((BB * CCH * NN) / (256 * 8)), dim3(256), 0, stream>>>(X, pe, XpH);
    k_projm<<<dim3(NN / 128, 3, BB), dim3(256), 0, stream>>>(
        XpH, tq, tk, tv, wpackh, bpack, qt, kk, vv);
    k_kv<<<dim3(KVS, BB), dim3(256), 0, stream>>>(kk, vv, Mpart);
    k_kvred<<<dim3(8, BB), dim3(256), 0, stream>>>(Mpart, Mt);
    k_qmfinal<<<dim3(32, 2, BB), dim3(256), 0, stream>>>(qt, Mt, Woh, X, out);
}